// Round 1
// baseline (1324.340 us; speedup 1.0000x reference)
//
#include <hip/hip_runtime.h>
#include <hip/hip_bf16.h>

// Problem constants (reference: B,C,H = 4,512,4096; IC = C/2)
constexpr int BB = 4;
constexpr int CC = 512;
constexpr int HH = 4096;
constexpr int IC = 256;

// ---------------------------------------------------------------------------
// Load-with-convert helpers (A operand may be fp32 or bf16)
// ---------------------------------------------------------------------------
__device__ inline float ldconv(const float* p) { return *p; }
__device__ inline float ldconv(const __hip_bfloat16* p) { return __bfloat162float(*p); }

// ---------------------------------------------------------------------------
// Tiled GEMM: 64x64 output tile, 256 threads, 4x4 per thread, Ktile=16.
// A: [M,K] k-contiguous.
// B: MODE != 4 -> [K,N] n-contiguous (NN).  MODE == 4 -> [N,K] k-contiguous (NT).
// MODE 0: v += bias[m];  store outF[b*sOb + m*N + n]          (phi)
// MODE 1: v += bias[m];  store outF[b*sOb + n*M + m]          (theta / g, transposed)
// MODE 2: store outBf[b*sOb + m*N + n] = bf16(exp(v))         (scores -> E)
// MODE 3: store outF[b*sOb + m*N + n]                          (ag)
// MODE 4: v += bias[m] + xadd[b*C*H + m*N + n]; store outF     (final + residual)
// All of M,N multiples of 64; K multiple of 16 (holds for every call here).
// ---------------------------------------------------------------------------
template <typename AT, int MODE>
__launch_bounds__(256)
__global__ void gemm64(const AT* __restrict__ Aall, const float* __restrict__ Ball,
                       float* __restrict__ outF, __hip_bfloat16* __restrict__ outBf,
                       const float* __restrict__ bias, const float* __restrict__ xadd,
                       int M, int N, int K,
                       size_t sAb, size_t sBb, size_t sOb) {
  const int b = blockIdx.z;
  const AT* __restrict__ A = Aall + (size_t)b * sAb;
  const float* __restrict__ Bm = Ball + (size_t)b * sBb;

  const int tid = threadIdx.x;
  const int tx = tid & 15;       // n quadrant
  const int ty = tid >> 4;       // m quadrant
  const int mBase = blockIdx.y * 64;
  const int nBase = blockIdx.x * 64;

  // pad 68: float4-aligned rows, worst LDS aliasing is 2-way (free on CDNA4)
  __shared__ float As[16][68];   // [k][m]
  __shared__ float Bs[16][68];   // [k][n]

  float acc[4][4] = {};

  const int lk = tid & 15;       // k lane for A-style loads
  const int lm = tid >> 4;       // 0..15
  const int lnB = tid & 63;      // n lane for NN B loads
  const int lkB = tid >> 6;      // 0..3

  for (int k0 = 0; k0 < K; k0 += 16) {
#pragma unroll
    for (int j = 0; j < 4; ++j) {
      const int m = mBase + lm + j * 16;
      As[lk][lm + j * 16] = ldconv(&A[(size_t)m * K + (k0 + lk)]);
    }
    if constexpr (MODE == 4) {
#pragma unroll
      for (int j = 0; j < 4; ++j) {
        const int n = nBase + lm + j * 16;
        Bs[lk][lm + j * 16] = Bm[(size_t)n * K + (k0 + lk)];
      }
    } else {
#pragma unroll
      for (int j = 0; j < 4; ++j) {
        const int k = k0 + lkB + j * 4;
        Bs[lkB + j * 4][lnB] = Bm[(size_t)k * N + (nBase + lnB)];
      }
    }
    __syncthreads();
#pragma unroll
    for (int kk = 0; kk < 16; ++kk) {
      const float4 a4 = *reinterpret_cast<const float4*>(&As[kk][ty * 4]);
      const float4 b4 = *reinterpret_cast<const float4*>(&Bs[kk][tx * 4]);
      const float a[4] = {a4.x, a4.y, a4.z, a4.w};
      const float bv[4] = {b4.x, b4.y, b4.z, b4.w};
#pragma unroll
      for (int i = 0; i < 4; ++i)
#pragma unroll
        for (int j = 0; j < 4; ++j) acc[i][j] += a[i] * bv[j];
    }
    __syncthreads();
  }

#pragma unroll
  for (int i = 0; i < 4; ++i) {
    const int m = mBase + ty * 4 + i;
#pragma unroll
    for (int j = 0; j < 4; ++j) {
      const int n = nBase + tx * 4 + j;
      float v = acc[i][j];
      if constexpr (MODE == 0) {
        v += bias[m];
        outF[(size_t)b * sOb + (size_t)m * N + n] = v;
      } else if constexpr (MODE == 1) {
        v += bias[m];
        outF[(size_t)b * sOb + (size_t)n * M + m] = v;
      } else if constexpr (MODE == 2) {
        outBf[(size_t)b * sOb + (size_t)m * N + n] = __float2bfloat16(__expf(v));
      } else if constexpr (MODE == 3) {
        outF[(size_t)b * sOb + (size_t)m * N + n] = v;
      } else {
        v += bias[m] + xadd[(size_t)b * ((size_t)CC * HH) + (size_t)m * N + n];
        outF[(size_t)b * sOb + (size_t)m * N + n] = v;
      }
    }
  }
}

// ---------------------------------------------------------------------------
// Column sums of E over q: Z[b*H + k] = sum_q E[b,q,k]. grid = (B*H/256, 16).
// Z must be zeroed first (hipMemsetAsync).
// ---------------------------------------------------------------------------
__launch_bounds__(256)
__global__ void colsum_kernel(const __hip_bfloat16* __restrict__ E, float* __restrict__ Z) {
  const int idx = blockIdx.x * 256 + threadIdx.x;   // 0 .. B*H-1
  const int b = idx >> 12;                          // / H
  const int k = idx & (HH - 1);
  const __hip_bfloat16* p = E + (size_t)b * HH * HH + k;
  const int q0 = blockIdx.y * 256;
  float s = 0.f;
#pragma unroll 8
  for (int q = q0; q < q0 + 256; ++q) s += __bfloat162float(p[(size_t)q * HH]);
  atomicAdd(&Z[idx], s);
}

// g[b,k,i] /= Z[b*H + k]   (folds the softmax denominator into g)
__launch_bounds__(256)
__global__ void gscale_kernel(float* __restrict__ g, const float* __restrict__ Z) {
  const int idx = blockIdx.x * 256 + threadIdx.x;   // 0 .. B*H*IC-1
  const int bk = idx >> 8;                          // / IC
  g[idx] = g[idx] / Z[bk];
}

// ---------------------------------------------------------------------------
// Launch
// ---------------------------------------------------------------------------
extern "C" void kernel_launch(void* const* d_in, const int* in_sizes, int n_in,
                              void* d_out, int out_size, void* d_ws, size_t ws_size,
                              hipStream_t stream) {
  (void)in_sizes; (void)n_in; (void)out_size;

  const float* x       = (const float*)d_in[0];
  const float* w_phi   = (const float*)d_in[1];
  const float* b_phi   = (const float*)d_in[2];
  const float* w_theta = (const float*)d_in[3];
  const float* b_theta = (const float*)d_in[4];
  const float* w_g     = (const float*)d_in[5];
  const float* b_g     = (const float*)d_in[6];
  const float* w_mask  = (const float*)d_in[7];
  const float* b_mask  = (const float*)d_in[8];
  float* out = (float*)d_out;

  // Workspace layout (needs ~202 MB):
  //   phi   [B,IC,H] fp32   16 MB
  //   theta [B,H,IC] fp32   16 MB
  //   g     [B,H,IC] fp32   16 MB
  //   ag    [B,H,IC] fp32   16 MB
  //   Z     [B,H]    fp32   64 KB
  //   E     [B,H,H]  bf16  134 MB
  const size_t nProj = (size_t)BB * HH * IC;  // 4,194,304
  float* phi   = (float*)d_ws;
  float* theta = phi + nProj;
  float* g     = theta + nProj;
  float* ag    = g + nProj;
  float* Z     = ag + nProj;
  __hip_bfloat16* E = (__hip_bfloat16*)(Z + (size_t)BB * HH);
  (void)ws_size;  // requires ws_size >= ~202 MB

  const dim3 blk(256);

  // 1) Projections. M=IC, N=H, K=C.  A = weights (shared across b), B = x[b].
  {
    dim3 grid(HH / 64, IC / 64, BB);
    // phi[b,i,h]  (natural store)
    gemm64<float, 0><<<grid, blk, 0, stream>>>(w_phi, x, phi, nullptr, b_phi, nullptr,
                                               IC, HH, CC, 0, (size_t)CC * HH, (size_t)IC * HH);
    // theta[b,h,i] (transposed store)
    gemm64<float, 1><<<grid, blk, 0, stream>>>(w_theta, x, theta, nullptr, b_theta, nullptr,
                                               IC, HH, CC, 0, (size_t)CC * HH, (size_t)HH * IC);
    // g[b,h,i] (transposed store)
    gemm64<float, 1><<<grid, blk, 0, stream>>>(w_g, x, g, nullptr, b_g, nullptr,
                                               IC, HH, CC, 0, (size_t)CC * HH, (size_t)HH * IC);
  }

  // 2) Scores + exp: E[b,q,k] = exp(theta[b,q,:] . phi[b,:,k])  (bf16 store)
  {
    dim3 grid(HH / 64, HH / 64, BB);
    gemm64<float, 2><<<grid, blk, 0, stream>>>(theta, phi, nullptr, E, nullptr, nullptr,
                                               HH, HH, IC, (size_t)HH * IC, (size_t)IC * HH,
                                               (size_t)HH * HH);
  }

  // 3) Softmax denominators over the QUERY axis: Z[b,k] = sum_q E[b,q,k]
  hipMemsetAsync(Z, 0, (size_t)BB * HH * sizeof(float), stream);
  {
    dim3 grid((BB * HH) / 256, 16);
    colsum_kernel<<<grid, blk, 0, stream>>>(E, Z);
  }

  // 4) Fold denominator into g: g[b,k,i] /= Z[b,k]
  gscale_kernel<<<dim3((BB * HH * IC) / 256), blk, 0, stream>>>(g, Z);

  // 5) ag[b,q,i] = sum_k E[b,q,k] * g'[b,k,i].  M=H, N=IC, K=H, A is bf16.
  {
    dim3 grid(IC / 64, HH / 64, BB);
    gemm64<__hip_bfloat16, 3><<<grid, blk, 0, stream>>>(E, g, ag, nullptr, nullptr, nullptr,
                                                        HH, IC, HH, (size_t)HH * HH,
                                                        (size_t)HH * IC, (size_t)HH * IC);
  }

  // 6) out[b,c,h] = w_mask[c,:] . ag[b,h,:] + b_mask[c] + x[b,c,h]   (NT GEMM)
  {
    dim3 grid(HH / 64, CC / 64, BB);
    gemm64<float, 4><<<grid, blk, 0, stream>>>(w_mask, ag, out, nullptr, b_mask, x,
                                               CC, HH, IC, 0, (size_t)HH * IC, (size_t)CC * HH);
  }
}

// Round 2
// 326.523 us; speedup vs baseline: 4.0559x; 4.0559x over previous
//
#include <hip/hip_runtime.h>
#include <hip/hip_bf16.h>
#include <hip/hip_fp16.h>
#include <type_traits>

constexpr int BB = 4;
constexpr int CC = 512;
constexpr int HH = 4096;
constexpr int IC = 256;

typedef _Float16 f16x8v __attribute__((ext_vector_type(8)));
typedef __bf16   bf16x8v __attribute__((ext_vector_type(8)));
typedef float    f32x4v __attribute__((ext_vector_type(4)));

// ---------------------------------------------------------------------------
// async global -> LDS, 16 bytes per lane (verified pattern: m03/m97)
// ---------------------------------------------------------------------------
__device__ __forceinline__ void gll16(const void* g, void* l) {
  __builtin_amdgcn_global_load_lds(
      (const __attribute__((address_space(1))) unsigned int*)g,
      (__attribute__((address_space(3))) unsigned int*)l, 16, 0, 0);
}

__device__ __forceinline__ f32x4v mfma16(f16x8v a, f16x8v b, f32x4v c) {
  return __builtin_amdgcn_mfma_f32_16x16x32_f16(a, b, c, 0, 0, 0);
}
__device__ __forceinline__ f32x4v mfma16(bf16x8v a, bf16x8v b, f32x4v c) {
  return __builtin_amdgcn_mfma_f32_16x16x32_bf16(a, b, c, 0, 0, 0);
}

// ---------------------------------------------------------------------------
// 128x128-tile B^T GEMM: C[m,n] = sum_k A[m,k] * B[n,k]; A,B k-contiguous.
// 256 threads = 4 waves, each wave a 64x64 quadrant (4x4 MFMA tiles).
// MODE 0: fp16 store  out[m*N+n] = v + bias[n]        (theta / phi proj)
// MODE 1: bf16 store  out[m*N+n] = v + bias[m]        (g proj, [IC,H])
// MODE 2: bf16 store  out[m*N+n] = exp(v); Z[b,n] += column sums (scores)
// MODE 3: fp32 store  out[m*N+n] = v + bias[m] + xres (final + residual)
// Element type: fp16 for MODE 0/1/2, bf16 for MODE 3.
// ---------------------------------------------------------------------------
template <int MODE>
__launch_bounds__(256)
__global__ void mgemm128(const void* __restrict__ Aall, const void* __restrict__ Ball,
                         void* __restrict__ outP, const float* __restrict__ bias,
                         const float* __restrict__ xres, float* __restrict__ Z,
                         int M, int N, int K,
                         size_t sAb, size_t sBb, size_t sOb) {
  using ET = typename std::conditional<MODE == 3, bf16x8v, f16x8v>::type;

  __shared__ __align__(16) unsigned short sA[128 * 32];
  __shared__ __align__(16) unsigned short sB[128 * 32];

  const int b = blockIdx.z;
  const unsigned short* __restrict__ A = (const unsigned short*)Aall + (size_t)b * sAb;
  const unsigned short* __restrict__ Bm = (const unsigned short*)Ball + (size_t)b * sBb;

  const int t = threadIdx.x;
  const int lane = t & 63;
  const int w = t >> 6;
  const int wm = (w >> 1) << 6;
  const int wn = (w & 1) << 6;
  const int mBase = blockIdx.y * 128;
  const int nBase = blockIdx.x * 128;

  const int fr = lane & 15;
  const int fo = (lane >> 4) << 3;

  f32x4v acc[4][4] = {};

  for (int k0 = 0; k0 < K; k0 += 32) {
#pragma unroll
    for (int p = 0; p < 2; ++p) {
      const int u = t + (p << 8);
      const int r = u >> 2;
      const int cs = (u & 3) << 3;
      gll16(A + (size_t)(mBase + r) * K + (k0 + cs), sA + u * 8);
      gll16(Bm + (size_t)(nBase + r) * K + (k0 + cs), sB + u * 8);
    }
    __syncthreads();
    ET af[4], bf[4];
#pragma unroll
    for (int i = 0; i < 4; ++i)
      af[i] = *(const ET*)(sA + ((wm + (i << 4) + fr) << 5) + fo);
#pragma unroll
    for (int j = 0; j < 4; ++j)
      bf[j] = *(const ET*)(sB + ((wn + (j << 4) + fr) << 5) + fo);
#pragma unroll
    for (int i = 0; i < 4; ++i)
#pragma unroll
      for (int j = 0; j < 4; ++j)
        acc[i][j] = mfma16(af[i], bf[j], acc[i][j]);
    __syncthreads();
  }

  // Epilogue. C/D layout (verified m89/m91): col = lane&15, row = (lane>>4)*4 + reg
  const int row0 = (lane >> 4) << 2;
  const int col = lane & 15;

  if constexpr (MODE == 2) {
    __hip_bfloat16* __restrict__ outB = (__hip_bfloat16*)outP;
    float csum[4] = {0.f, 0.f, 0.f, 0.f};
#pragma unroll
    for (int i = 0; i < 4; ++i) {
      const int m0 = mBase + wm + (i << 4) + row0;
#pragma unroll
      for (int j = 0; j < 4; ++j) {
        const int n = nBase + wn + (j << 4) + col;
        __hip_bfloat16* dst = outB + (size_t)b * sOb + (size_t)m0 * N + n;
#pragma unroll
        for (int rg = 0; rg < 4; ++rg) {
          const float e = __expf(acc[i][j][rg]);
          dst[(size_t)rg * N] = __float2bfloat16(e);
          csum[j] += e;
        }
      }
    }
#pragma unroll
    for (int j = 0; j < 4; ++j) {
      float s = csum[j];
      s += __shfl_xor(s, 16, 64);
      s += __shfl_xor(s, 32, 64);
      if (lane < 16) {
        const int n = nBase + wn + (j << 4) + col;
        atomicAdd(&Z[(size_t)b * N + n], s);
      }
    }
  } else {
#pragma unroll
    for (int i = 0; i < 4; ++i) {
      const int m0 = mBase + wm + (i << 4) + row0;
#pragma unroll
      for (int j = 0; j < 4; ++j) {
        const int n = nBase + wn + (j << 4) + col;
#pragma unroll
        for (int rg = 0; rg < 4; ++rg) {
          const int m = m0 + rg;
          const float v = acc[i][j][rg];
          if constexpr (MODE == 0) {
            ((__half*)outP)[(size_t)b * sOb + (size_t)m * N + n] = __float2half(v + bias[n]);
          } else if constexpr (MODE == 1) {
            ((__hip_bfloat16*)outP)[(size_t)b * sOb + (size_t)m * N + n] =
                __float2bfloat16(v + bias[m]);
          } else {
            const size_t o = (size_t)b * sOb + (size_t)m * N + n;
            ((float*)outP)[o] = v + bias[m] + xres[o];
          }
        }
      }
    }
  }
}

// ---------------------------------------------------------------------------
// ag GEMM: tile 64(m) x 256(n), K = H = 4096. A = E [H,H] bf16, B = gs [IC,H]
// bf16 (both k-contiguous). E is read exactly once (full IC per block).
// 4 waves side-by-side in n. out: agB[b,m,n] bf16 [H,IC].
// ---------------------------------------------------------------------------
__launch_bounds__(256)
__global__ void mgemm_ag(const __hip_bfloat16* __restrict__ Eall,
                         const __hip_bfloat16* __restrict__ Gall,
                         __hip_bfloat16* __restrict__ outB) {
  __shared__ __align__(16) unsigned short sA[64 * 32];
  __shared__ __align__(16) unsigned short sB[256 * 32];

  const int b = blockIdx.z;
  const unsigned short* __restrict__ A =
      (const unsigned short*)Eall + (size_t)b * HH * HH;
  const unsigned short* __restrict__ G =
      (const unsigned short*)Gall + (size_t)b * IC * HH;

  const int t = threadIdx.x;
  const int lane = t & 63;
  const int w = t >> 6;
  const int wn = w << 6;
  const int mBase = blockIdx.y * 64;

  const int fr = lane & 15;
  const int fo = (lane >> 4) << 3;

  f32x4v acc[4][4] = {};

#pragma unroll 2
  for (int k0 = 0; k0 < HH; k0 += 32) {
    {
      const int r = t >> 2;
      const int cs = (t & 3) << 3;
      gll16(A + (size_t)(mBase + r) * HH + (k0 + cs), sA + t * 8);
    }
#pragma unroll
    for (int p = 0; p < 4; ++p) {
      const int u = t + (p << 8);
      const int r = u >> 2;
      const int cs = (u & 3) << 3;
      gll16(G + (size_t)r * HH + (k0 + cs), sB + u * 8);
    }
    __syncthreads();
    bf16x8v af[4], bf[4];
#pragma unroll
    for (int i = 0; i < 4; ++i)
      af[i] = *(const bf16x8v*)(sA + (((i << 4) + fr) << 5) + fo);
#pragma unroll
    for (int j = 0; j < 4; ++j)
      bf[j] = *(const bf16x8v*)(sB + ((wn + (j << 4) + fr) << 5) + fo);
#pragma unroll
    for (int i = 0; i < 4; ++i)
#pragma unroll
      for (int j = 0; j < 4; ++j)
        acc[i][j] = mfma16(af[i], bf[j], acc[i][j]);
    __syncthreads();
  }

  const int row0 = (lane >> 4) << 2;
  const int col = lane & 15;
#pragma unroll
  for (int i = 0; i < 4; ++i) {
#pragma unroll
    for (int j = 0; j < 4; ++j) {
      const int n = wn + (j << 4) + col;
#pragma unroll
      for (int rg = 0; rg < 4; ++rg) {
        const int m = mBase + (i << 4) + row0 + rg;
        outB[(size_t)b * HH * IC + (size_t)m * IC + n] = __float2bfloat16(acc[i][j][rg]);
      }
    }
  }
}

// ---------------------------------------------------------------------------
// x [B,C,H] fp32 -> xT [B,H,C] fp16   (64x64 LDS transpose tiles)
// ---------------------------------------------------------------------------
__launch_bounds__(256)
__global__ void xpose(const float* __restrict__ x, __half* __restrict__ xT) {
  __shared__ float tile[64][65];
  const int b = blockIdx.z;
  const int h0 = blockIdx.x * 64;
  const int c0 = blockIdx.y * 64;
  const int lane = threadIdx.x & 63;
  const int r0 = threadIdx.x >> 6;
  const float* xb = x + (size_t)b * CC * HH;
#pragma unroll
  for (int rr = 0; rr < 16; ++rr) {
    const int c = r0 * 16 + rr;
    tile[c][lane] = xb[(size_t)(c0 + c) * HH + h0 + lane];
  }
  __syncthreads();
  __half* ob = xT + (size_t)b * HH * CC;
#pragma unroll
  for (int rr = 0; rr < 16; ++rr) {
    const int hl = r0 * 16 + rr;
    ob[(size_t)(h0 + hl) * CC + c0 + lane] = __float2half(tile[lane][hl]);
  }
}

// ---------------------------------------------------------------------------
// weight converts: w_phi/w_theta/w_g -> fp16, w_mask -> bf16 (all 131072 elems)
// ---------------------------------------------------------------------------
__global__ void convw(const float* __restrict__ s0, const float* __restrict__ s1,
                      const float* __restrict__ s2, const float* __restrict__ s3,
                      __half* __restrict__ d0, __half* __restrict__ d1,
                      __half* __restrict__ d2, __hip_bfloat16* __restrict__ d3) {
  const int which = blockIdx.y;
  const int i = (blockIdx.x * 256 + threadIdx.x) * 4;
  if (which < 3) {
    const float* s = which == 0 ? s0 : (which == 1 ? s1 : s2);
    __half* d = which == 0 ? d0 : (which == 1 ? d1 : d2);
    const float4 v = *(const float4*)(s + i);
    d[i] = __float2half(v.x); d[i + 1] = __float2half(v.y);
    d[i + 2] = __float2half(v.z); d[i + 3] = __float2half(v.w);
  } else {
    const float4 v = *(const float4*)(s3 + i);
    d3[i] = __float2bfloat16(v.x); d3[i + 1] = __float2bfloat16(v.y);
    d3[i + 2] = __float2bfloat16(v.z); d3[i + 3] = __float2bfloat16(v.w);
  }
}

// ---------------------------------------------------------------------------
// gB [B,IC,H] bf16 /= Z[b,h]  (in place, 8 elems per thread)
// ---------------------------------------------------------------------------
__launch_bounds__(256)
__global__ void gscale(unsigned int* __restrict__ g, const float* __restrict__ Z) {
  const size_t tid = (size_t)blockIdx.x * 256 + threadIdx.x;
  const size_t e0 = tid * 8;
  const int b = (int)(e0 >> 20);            // IC*H = 2^20
  const int h = (int)(e0 & (HH - 1));
  const float* Zp = Z + ((size_t)b << 12) + h;
  uint4 raw = ((const uint4*)g)[tid];
  unsigned short* u = (unsigned short*)&raw;
#pragma unroll
  for (int k = 0; k < 8; ++k) {
    const float f = __uint_as_float(((unsigned)u[k]) << 16) / Zp[k];
    const __hip_bfloat16 hb = __float2bfloat16(f);
    unsigned short bits;
    __builtin_memcpy(&bits, &hb, 2);
    u[k] = bits;
  }
  ((uint4*)g)[tid] = raw;
}

// ---------------------------------------------------------------------------
extern "C" void kernel_launch(void* const* d_in, const int* in_sizes, int n_in,
                              void* d_out, int out_size, void* d_ws, size_t ws_size,
                              hipStream_t stream) {
  (void)in_sizes; (void)n_in; (void)out_size; (void)ws_size;

  const float* x       = (const float*)d_in[0];
  const float* w_phi   = (const float*)d_in[1];
  const float* b_phi   = (const float*)d_in[2];
  const float* w_theta = (const float*)d_in[3];
  const float* b_theta = (const float*)d_in[4];
  const float* w_g     = (const float*)d_in[5];
  const float* b_g     = (const float*)d_in[6];
  const float* w_mask  = (const float*)d_in[7];
  const float* b_mask  = (const float*)d_in[8];
  float* out = (float*)d_out;

  // workspace layout (~186 MB; round-1 proved >=198 MB available)
  char* p = (char*)d_ws;
  __hip_bfloat16* E = (__hip_bfloat16*)p;           p += (size_t)BB * HH * HH * 2;   // 134.2 MB
  __half* xT       = (__half*)p;                    p += (size_t)BB * HH * CC * 2;   // 16.8 MB
  __half* thetaH   = (__half*)p;                    p += (size_t)BB * HH * IC * 2;   // 8.4 MB
  __half* phiH     = (__half*)p;                    p += (size_t)BB * HH * IC * 2;
  __hip_bfloat16* gB  = (__hip_bfloat16*)p;         p += (size_t)BB * IC * HH * 2;
  __hip_bfloat16* agB = (__hip_bfloat16*)p;         p += (size_t)BB * HH * IC * 2;
  __half* wthH = (__half*)p;                        p += (size_t)IC * CC * 2;
  __half* wphH = (__half*)p;                        p += (size_t)IC * CC * 2;
  __half* wgH  = (__half*)p;                        p += (size_t)IC * CC * 2;
  __hip_bfloat16* wmB = (__hip_bfloat16*)p;         p += (size_t)CC * IC * 2;
  float* Z = (float*)p;                             p += (size_t)BB * HH * 4;

  const dim3 blk(256);

  // weights -> fp16 / bf16
  convw<<<dim3(128, 4), blk, 0, stream>>>(w_phi, w_theta, w_g, w_mask, wphH, wthH, wgH, wmB);
  // x -> xT fp16
  xpose<<<dim3(HH / 64, CC / 64, BB), blk, 0, stream>>>(x, xT);

  // theta[h,i] = xT[h,:] . w_theta[i,:] + b_theta[i]
  mgemm128<0><<<dim3(IC / 128, HH / 128, BB), blk, 0, stream>>>(
      xT, wthH, thetaH, b_theta, nullptr, nullptr,
      HH, IC, CC, (size_t)HH * CC, 0, (size_t)HH * IC);
  // phi[h,i]
  mgemm128<0><<<dim3(IC / 128, HH / 128, BB), blk, 0, stream>>>(
      xT, wphH, phiH, b_phi, nullptr, nullptr,
      HH, IC, CC, (size_t)HH * CC, 0, (size_t)HH * IC);
  // g[i,h] = w_g[i,:] . xT[h,:] + b_g[i]   (bf16, [IC,H])
  mgemm128<1><<<dim3(HH / 128, IC / 128, BB), blk, 0, stream>>>(
      wgH, xT, gB, b_g, nullptr, nullptr,
      IC, HH, CC, 0, (size_t)HH * CC, (size_t)IC * HH);

  // scores -> E = exp(theta . phi^T), Z[b,k] = sum_q E[q,k]
  hipMemsetAsync(Z, 0, (size_t)BB * HH * sizeof(float), stream);
  mgemm128<2><<<dim3(HH / 128, HH / 128, BB), blk, 0, stream>>>(
      thetaH, phiH, E, nullptr, nullptr, Z,
      HH, HH, IC, (size_t)HH * IC, (size_t)HH * IC, (size_t)HH * HH);

  // g /= Z
  gscale<<<dim3((BB * IC * HH / 8) / 256), blk, 0, stream>>>((unsigned int*)gB, Z);

  // ag[q,i] = sum_k E[q,k] * gs[i,k]
  mgemm_ag<<<dim3(1, HH / 64, BB), blk, 0, stream>>>(E, gB, agB);

  // out[c,h] = w_mask[c,:] . ag[h,:] + b_mask[c] + x[c,h]
  mgemm128<3><<<dim3(HH / 128, CC / 128, BB), blk, 0, stream>>>(
      wmB, agB, out, b_mask, x, nullptr,
      CC, HH, IC, 0, (size_t)HH * IC, (size_t)CC * HH);
}